// Round 1
// baseline (254.740 us; speedup 1.0000x reference)
//
#include <hip/hip_runtime.h>

// Positional encoding off-grid: out[c, i] layout (256, num), row-major, fp32.
//   c in [0,128):   c=2k -> sin(y_i * f_k), c=2k+1 -> cos(y_i * f_k)
//   c in [128,256): c-128=2k -> sin(x_i * f_k), else cos(x_i * f_k)
// Write-BW bound: 256 MiB out, ~2 MiB in. Floor ~43 us @ 6.3 TB/s.

__global__ __launch_bounds__(256) void pe_offgrid_kernel(
    const float* __restrict__ YX,        // (2, num)
    const float* __restrict__ inv_freq,  // (64,)
    float* __restrict__ out,             // (256, num)
    int num)
{
    __shared__ float fshared[64];
    if (threadIdx.x < 64) fshared[threadIdx.x] = inv_freq[threadIdx.x];
    __syncthreads();

    const int i4 = blockIdx.x * blockDim.x + threadIdx.x;  // float4 chunk over i
    if (4 * i4 >= num) return;

    const int slice = blockIdx.y;        // 0..7, each covers 16 of the 128 (coord,k) pairs
    const int kk0   = slice * 16;
    const bool isY  = (kk0 < 64);

    // coord values for the 4 consecutive i's this thread owns
    const float4 c4 = ((const float4*)(YX + (isY ? 0 : num)))[i4];
    const size_t col = (size_t)(4 * i4);
    const size_t rowBase = isY ? 0 : 128;

#pragma unroll
    for (int j = 0; j < 16; ++j) {
        const int kk = kk0 + j;
        const int k  = kk & 63;          // frequency index
        const float fr = fshared[k];

        float4 s, c;
        __sincosf(c4.x * fr, &s.x, &c.x);
        __sincosf(c4.y * fr, &s.y, &c.y);
        __sincosf(c4.z * fr, &s.z, &c.z);
        __sincosf(c4.w * fr, &s.w, &c.w);

        const size_t rowS = (rowBase + (size_t)(2 * k)) * (size_t)num + col;
        *(float4*)(out + rowS)       = s;   // sin row (c = 2k [+128])
        *(float4*)(out + rowS + num) = c;   // cos row (c = 2k+1 [+128])
    }
}

extern "C" void kernel_launch(void* const* d_in, const int* in_sizes, int n_in,
                              void* d_out, int out_size, void* d_ws, size_t ws_size,
                              hipStream_t stream) {
    const float* YX       = (const float*)d_in[0];
    const float* inv_freq = (const float*)d_in[1];
    float* out            = (float*)d_out;

    const int num = in_sizes[0] / 2;          // 262144
    const int i4_total = (num + 3) / 4;       // 65536
    dim3 block(256);
    dim3 grid((i4_total + block.x - 1) / block.x, 8);
    pe_offgrid_kernel<<<grid, block, 0, stream>>>(YX, inv_freq, out, num);
}